// Round 11
// baseline (43.620 us; speedup 1.0000x reference)
//
#include <hip/hip_runtime.h>
#include <math.h>

#define NOUT 64
#define NIN  64
#define HH   32
#define WW   32
#define XCPL 205                         // per-channel LDS plane stride (odd -> 2-way max)
#define XWORDS (6 * 34 * NIN)            // 13056 staged x words (rows i0-1..i0+4, cols -1..32)
#define NBLK 512                         // 64 f * 8 four-row bands

// block = 512 thr = (f, 4-row band); wave = 16-pixel row strip; lane = channel c.
// Weights: global -> registers, one record per (ab), reused for 16 pixels.
// x: LDS planar per-channel planes, 54 ds_read_b32 per 144 evals.
__global__ __launch_bounds__(512, 4) void kan_main(const float* __restrict__ x,
                                                   const float* __restrict__ wn,
                                                   const float* __restrict__ wd,
                                                   float* __restrict__ out) {
    __shared__ float xt[NIN * XCPL];     // 52480 B

    // bijective XCD-chunked swizzle: 512 blocks, 64 per XCD -> 8 f's per XCD L2
    int bid  = blockIdx.x;
    int wgid = (bid & 7) * (NBLK / 8) + (bid >> 3);
    int f    = wgid >> 3;
    int band = wgid & 7;
    int i0   = band * 4;

    int tid = threadIdx.x;

    // ---- stage x: rows i0-1..i0+4, cols -1..32, 64 c; global reads c-coalesced;
    // ---- LDS writes at lane-stride 205 words (odd) -> conflict-free ----
    for (int k = 0; k < 26; ++k) {
        int idx = k * 512 + tid;
        if (idx < XWORDS) {
            int c   = idx & 63;
            int t   = idx >> 6;          // 0..203
            int row = t / 34;
            int col = t % 34;
            int gi  = i0 - 1 + row;
            int gj  = col - 1;
            float v = 0.0f;
            if (gi >= 0 && gi < HH && gj >= 0 && gj < WW)
                v = x[(gi * WW + gj) * NIN + c];
            xt[c * XCPL + row * 34 + col] = v;
        }
    }
    __syncthreads();

    int lane = tid & 63;                 // = input channel c
    int wid  = tid >> 6;                 // 0..7
    int r    = wid >> 1;                 // pixel row within band: 0..3
    int j0   = (wid & 1) * 16;           // pixel-strip start col
    int c    = lane;

    float acc[16];
#pragma unroll
    for (int p = 0; p < 16; ++p) acc[p] = 0.0f;

    const float2* wn2 = (const float2*)(wn + (size_t)(f * NIN + c) * 54);
    const float4* wd4 = (const float4*)(wd + (size_t)(f * NIN + c) * 36);
    // staged col index for pixel p, window col b: j0 + p + b (0..33); row: r + a
    const float* xbase = &xt[c * XCPL + r * 34 + j0];

#pragma unroll
    for (int a = 0; a < 3; ++a) {
        float xr[18];
#pragma unroll
        for (int t = 0; t < 18; ++t)
            xr[t] = xbase[a * 34 + t];   // ds_read, imm offsets, conflict-free
#pragma unroll
        for (int b = 0; b < 3; ++b) {
            const int ab = a * 3 + b;
            float2 A01 = wn2[ab * 3 + 0];    // a0 a1   (global, L1-resident)
            float2 A23 = wn2[ab * 3 + 1];    // a2 a3
            float2 A45 = wn2[ab * 3 + 2];    // a4 a5
            float4 Bq  = wd4[ab];            // b0 b1 b2 b3
#pragma unroll
            for (int p = 0; p < 16; ++p) {
                float xv = xr[p + b];
                float pn = fmaf(A45.y, xv, A45.x);
                pn = fmaf(pn, xv, A23.y);
                pn = fmaf(pn, xv, A23.x);
                pn = fmaf(pn, xv, A01.y);
                pn = fmaf(pn, xv, A01.x);
                float qn = fmaf(Bq.w, xv, Bq.z);
                qn = fmaf(qn, xv, Bq.y);
                qn = fmaf(qn, xv, Bq.x);
                float den = 1.0f + fabsf(xv * qn);
                acc[p] = fmaf(pn, __builtin_amdgcn_rcpf(den), acc[p]);
            }
        }
    }

    // ---- reduce over lanes (channels); lane p writes pixel p ----
#pragma unroll
    for (int p = 0; p < 16; ++p) {
        float s = acc[p];
        s += __shfl_xor(s, 32, 64);
        s += __shfl_xor(s, 16, 64);
        s += __shfl_xor(s, 8, 64);
        s += __shfl_xor(s, 4, 64);
        s += __shfl_xor(s, 2, 64);
        s += __shfl_xor(s, 1, 64);
        if (lane == p) out[f * (HH * WW) + (i0 + r) * WW + j0 + p] = s;
    }
}

extern "C" void kernel_launch(void* const* d_in, const int* in_sizes, int n_in,
                              void* d_out, int out_size, void* d_ws, size_t ws_size,
                              hipStream_t stream) {
    const float* x  = (const float*)d_in[0];
    const float* wn = (const float*)d_in[1];
    const float* wd = (const float*)d_in[2];
    float* out = (float*)d_out;
    (void)d_ws; (void)ws_size; (void)in_sizes; (void)n_in; (void)out_size;

    kan_main<<<NBLK, 512, 0, stream>>>(x, wn, wd, out);
}